// Round 1
// baseline (22.052 us; speedup 1.0000x reference)
//
#include <hip/hip_runtime.h>
#include <math.h>

// Problem constants (from reference): N=32, CI=32, CO=32, H=64, W=64, K=2
#define NN 32
#define CI 32
#define CO 32
#define HH 64
#define WW 64

#define G    4            // co's per thread
#define COG  (CO / G)     // 8 co-groups (blockIdx.y)

// ---------------------------------------------------------------------------
// Kernel 1: W[co][ci][par] = softmax over ci of logits[co][ci][k1][k2]
// (par = k1*2 + k2, which is exactly the flattened last two dims of logits).
// Tiny: 128 independent (co,par) softmaxes over 32 values each.
// ---------------------------------------------------------------------------
__global__ void sumconv_weights(const float* __restrict__ logits,
                                float* __restrict__ Wout) {
    int t = threadIdx.x;            // 0..127
    if (t >= CO * 4) return;
    int co  = t >> 2;
    int par = t & 3;
    const float* base = logits + co * CI * 4 + par;

    float m = -1e30f;
#pragma unroll
    for (int ci = 0; ci < CI; ++ci) m = fmaxf(m, base[ci * 4]);

    float e[CI];
    float s = 0.0f;
#pragma unroll
    for (int ci = 0; ci < CI; ++ci) {
        e[ci] = __expf(base[ci * 4] - m);
        s += e[ci];
    }
    float inv = 1.0f / s;
#pragma unroll
    for (int ci = 0; ci < CI; ++ci)
        Wout[co * CI * 4 + ci * 4 + par] = e[ci] * inv;
}

// ---------------------------------------------------------------------------
// Kernel 2: out[n,co,h,w] = log( sum_ci W[co,ci,par(h,w)] * exp(x[n,ci,h,w]) )
//
// Each thread owns a 2x2 pixel quad (h..h+1, w..w+1) so all 4 parities are
// in-thread -> the weight read W[co][ci] (float4 = 4 parities) is
// wave-uniform -> scalar s_load_dwordx4, no LDS, no per-lane weight traffic.
// CO split into 8 groups of 4 across blockIdx.y for parallelism
// (262144 threads = 4 waves/SIMD). x re-reads across co-groups hit L2/L3.
// ---------------------------------------------------------------------------
__global__ __launch_bounds__(256) void sumconv_main(
        const float* __restrict__ x,
        const float* __restrict__ Wn,
        float* __restrict__ out) {
    const int qid = blockIdx.x * 256 + threadIdx.x;   // quad id, 0..32767
    const int n   = qid >> 10;                        // 1024 quads per image
    const int qq  = qid & 1023;
    const int h   = (qq >> 5) << 1;                   // even row
    const int w   = (qq & 31) << 1;                   // even col
    const int co_base = blockIdx.y * G;

    const float4* __restrict__ Wv = (const float4*)Wn;  // [co][ci] -> float4(par0..3)

    const float* xb = x + ((n * CI) * HH + h) * WW + w;

    float acc[4][G];
#pragma unroll
    for (int q = 0; q < 4; ++q)
#pragma unroll
        for (int j = 0; j < G; ++j) acc[q][j] = 0.0f;

    for (int ci = 0; ci < CI; ++ci) {
        const float2 v0 = *(const float2*)(xb + ci * HH * WW);
        const float2 v1 = *(const float2*)(xb + ci * HH * WW + WW);
        const float e00 = __expf(v0.x);
        const float e01 = __expf(v0.y);
        const float e10 = __expf(v1.x);
        const float e11 = __expf(v1.y);
#pragma unroll
        for (int j = 0; j < G; ++j) {
            const float4 wv = Wv[(co_base + j) * CI + ci];  // wave-uniform -> s_load
            acc[0][j] = fmaf(wv.x, e00, acc[0][j]);
            acc[1][j] = fmaf(wv.y, e01, acc[1][j]);
            acc[2][j] = fmaf(wv.z, e10, acc[2][j]);
            acc[3][j] = fmaf(wv.w, e11, acc[3][j]);
        }
    }

#pragma unroll
    for (int j = 0; j < G; ++j) {
        const int co = co_base + j;
        float* ob = out + ((n * CO + co) * HH + h) * WW + w;
        float2 r0, r1;
        r0.x = __logf(acc[0][j]);
        r0.y = __logf(acc[1][j]);
        r1.x = __logf(acc[2][j]);
        r1.y = __logf(acc[3][j]);
        *(float2*)ob        = r0;
        *(float2*)(ob + WW) = r1;
    }
}

extern "C" void kernel_launch(void* const* d_in, const int* in_sizes, int n_in,
                              void* d_out, int out_size, void* d_ws, size_t ws_size,
                              hipStream_t stream) {
    const float* x      = (const float*)d_in[0];
    const float* logits = (const float*)d_in[1];
    float* out = (float*)d_out;
    float* Wn  = (float*)d_ws;   // 32*32*4 floats = 16 KB scratch

    sumconv_weights<<<1, 128, 0, stream>>>(logits, Wn);

    dim3 grid(NN * (HH / 2) * (WW / 2) / 256, COG);   // (128, 8)
    sumconv_main<<<grid, 256, 0, stream>>>(x, Wn, out);
}